// Round 1
// 479.612 us; speedup vs baseline: 1.0942x; 1.0942x over previous
//
#include <hip/hip_runtime.h>

#define BS 512
#define SRC 36
#define H 1024
#define MID 4096
#define M_ROWS (BS * SRC)   // 18432
#define ALPHAF 8.0f
#define GAMMAF 0.98f
#define EPSF 1e-6f

typedef __bf16 bf16;
typedef __attribute__((ext_vector_type(4))) __bf16 bf16x4;
typedef __attribute__((ext_vector_type(4))) float f32x4;
typedef __attribute__((ext_vector_type(16))) float f32x16;
typedef __attribute__((ext_vector_type(4))) int i32x4;
typedef __attribute__((ext_vector_type(8))) int i32x8;

__device__ __forceinline__ float wave_reduce_sum(float v) {
    #pragma unroll
    for (int off = 32; off > 0; off >>= 1) v += __shfl_xor(v, off, 64);
    return v;
}

__device__ __forceinline__ unsigned char to_fp8(float v) {
    v = fminf(fmaxf(v, -440.f), 440.f);
    int p = __builtin_amdgcn_cvt_pk_fp8_f32(v, 0.f, 0, false);
    return (unsigned char)(p & 0xff);
}

// ---------------- sum(ru) ----------------
__global__ __launch_bounds__(256) void k_rusum(const float* __restrict__ ru,
                                               float* __restrict__ rusum) {
    int i = blockIdx.x * 256 + threadIdx.x;
    float v = ru[i];
    v = wave_reduce_sum(v);
    __shared__ float s[4];
    if ((threadIdx.x & 63) == 0) s[threadIdx.x >> 6] = v;
    __syncthreads();
    if (threadIdx.x == 0) atomicAdd(rusum, s[0] + s[1] + s[2] + s[3]);
}

// ---------------- gate: rg, ru_new, focal, ru_out, w ----------------
__global__ __launch_bounds__(64) void k_gate(const float* __restrict__ att,
                                             const float* __restrict__ ru,
                                             const float* __restrict__ rusum,
                                             float* __restrict__ w,
                                             float* __restrict__ ru_out) {
    int b = blockIdx.x;
    int s = threadIdx.x;
    float rg = 0.f, run = 0.f;
    if (s < SRC) {
        const f32x4* row = (const f32x4*)(att + ((size_t)b * SRC + s) * SRC);
        f32x4 acc4 = row[0];
        #pragma unroll
        for (int j = 1; j < 9; ++j) {
            f32x4 t = row[j];
            acc4.x += t.x; acc4.y += t.y; acc4.z += t.z; acc4.w += t.w;
        }
        rg = acc4.x + acc4.y + acc4.z + acc4.w;
        float scale = (*rusum == 0.0f) ? 1.0f : (1.0f / (1.0f + GAMMAF));
        run = (ru[b * SRC + s] * GAMMAF + rg) * scale;
    }
    float sa = (s < SRC) ? sqrtf(run) : 0.f;
    float S = wave_reduce_sum(sa);
    float T = wave_reduce_sum(run * sa);
    if (s < SRC) {
        float funcF = run * S - T;
        float aw = (funcF > 0.f) ? ALPHAF : (1.0f / ALPHAF);
        ru_out[b * SRC + s] = aw * run;
        w[b * SRC + s] = aw * rg;
    }
}

// ---------------- transpose f32 [rows][cols] -> fp8 [cols][rows] with scale ----------------
__global__ __launch_bounds__(256) void k_transpose_fp8(const float* __restrict__ in,
                                                       unsigned char* __restrict__ out,
                                                       int rows, int cols, float scale) {
    __shared__ float tile[32][33];
    int bx = blockIdx.x * 32, by = blockIdx.y * 32;
    int tx = threadIdx.x;
    #pragma unroll
    for (int j = threadIdx.y; j < 32; j += 8)
        tile[j][tx] = in[(size_t)(by + j) * cols + bx + tx];
    __syncthreads();
    #pragma unroll
    for (int j = threadIdx.y; j < 32; j += 8)
        out[(size_t)(bx + j) * rows + by + tx] = to_fp8(tile[tx][j] * scale);
}

// ---------------- LN1, wave-per-row: mm (bf16) + mm8 (fp8 /8) ----------------
__global__ __launch_bounds__(256) void k_ln1(const f32x4* __restrict__ v,
                                             const f32x4* __restrict__ q,
                                             const f32x4* __restrict__ g1,
                                             const f32x4* __restrict__ b1,
                                             const float* __restrict__ w,
                                             bf16x4* __restrict__ mm,
                                             int* __restrict__ mm8) {
    const int lane = threadIdx.x & 63;
    const int row  = blockIdx.x * 4 + (threadIdx.x >> 6);
    const size_t base = (size_t)row * 256;
    f32x4 x[4];
    float sum = 0.f, sq = 0.f;
    #pragma unroll
    for (int p = 0; p < 4; ++p) {
        int g = lane + p * 64;
        f32x4 a = v[base + g];
        f32x4 b = q[base + g];
        a.x += b.x; a.y += b.y; a.z += b.z; a.w += b.w;
        x[p] = a;
        sum += a.x + a.y + a.z + a.w;
        sq  += a.x * a.x + a.y * a.y + a.z * a.z + a.w * a.w;
    }
    sum = wave_reduce_sum(sum);
    sq  = wave_reduce_sum(sq);
    float mu  = sum * (1.0f / H);
    float var = sq * (1.0f / H) - mu * mu;
    float inv = rsqrtf(var + EPSF);
    float ww = w[row];
    #pragma unroll
    for (int p = 0; p < 4; ++p) {
        int g = lane + p * 64;
        f32x4 gg = g1[g], bb = b1[g];
        float o0 = ww * ((x[p].x - mu) * inv * gg.x + bb.x);
        float o1 = ww * ((x[p].y - mu) * inv * gg.y + bb.y);
        float o2 = ww * ((x[p].z - mu) * inv * gg.z + bb.z);
        float o3 = ww * ((x[p].w - mu) * inv * gg.w + bb.w);
        bf16x4 o; o.x = (bf16)o0; o.y = (bf16)o1; o.z = (bf16)o2; o.w = (bf16)o3;
        mm[base + g] = o;
        float c0 = fminf(fmaxf(o0 * 0.125f, -440.f), 440.f);
        float c1 = fminf(fmaxf(o1 * 0.125f, -440.f), 440.f);
        float c2 = fminf(fmaxf(o2 * 0.125f, -440.f), 440.f);
        float c3 = fminf(fmaxf(o3 * 0.125f, -440.f), 440.f);
        int pk = __builtin_amdgcn_cvt_pk_fp8_f32(c0, c1, 0, false);
        pk = __builtin_amdgcn_cvt_pk_fp8_f32(c2, c3, pk, true);
        mm8[base + g] = pk;
    }
}

// ---------------- LN2, wave-per-row: out = LN(mm + fc), fc in bf16 ----------------
__global__ __launch_bounds__(256) void k_ln2(float* __restrict__ out,
                                             const bf16x4* __restrict__ fc,
                                             const bf16x4* __restrict__ mm,
                                             const f32x4* __restrict__ g2,
                                             const f32x4* __restrict__ b2) {
    const int lane = threadIdx.x & 63;
    const int row  = blockIdx.x * 4 + (threadIdx.x >> 6);
    const size_t base = (size_t)row * 256;
    f32x4 x[4];
    float sum = 0.f, sq = 0.f;
    #pragma unroll
    for (int p = 0; p < 4; ++p) {
        int g = lane + p * 64;
        bf16x4 a = fc[base + g];
        bf16x4 b = mm[base + g];
        f32x4 t;
        t.x = (float)a.x + (float)b.x;
        t.y = (float)a.y + (float)b.y;
        t.z = (float)a.z + (float)b.z;
        t.w = (float)a.w + (float)b.w;
        x[p] = t;
        sum += t.x + t.y + t.z + t.w;
        sq  += t.x * t.x + t.y * t.y + t.z * t.z + t.w * t.w;
    }
    sum = wave_reduce_sum(sum);
    sq  = wave_reduce_sum(sq);
    float mu  = sum * (1.0f / H);
    float var = sq * (1.0f / H) - mu * mu;
    float inv = rsqrtf(var + EPSF);
    f32x4* outv = (f32x4*)out;
    #pragma unroll
    for (int p = 0; p < 4; ++p) {
        int g = lane + p * 64;
        f32x4 gg = g2[g], bb = b2[g];
        f32x4 o;
        o.x = (x[p].x - mu) * inv * gg.x + bb.x;
        o.y = (x[p].y - mu) * inv * gg.y + bb.y;
        o.z = (x[p].z - mu) * inv * gg.z + bb.z;
        o.w = (x[p].w - mu) * inv * gg.w + bb.w;
        outv[base + g] = o;
    }
}

// ---------------- MX-fp8 MFMA GEMM: C[M,N] = A[M,K]*Bt[N,K]^T + bias ----------------
// 128x128 tile, BK=64, register-staged double-buffered LDS, 1 barrier/step.
// Uses mfma_scale_f32_32x32x64_f8f6f4 with unit scales (e8m0 127) -> identical
// math to plain fp8 MFMA at 2x the FLOP/cycle (4.69 PF vs 2.19 PF measured).
// LDS layout: plain K-contiguous rows, LDK=80 pad (5*row mod 8 bijective ->
// conflict-free ds_read_b128 for 32-consecutive-row fragment reads).
// Fragment: lane l holds row (l&31), 32 contiguous K bytes at half (l>>5)*32.
// OUTMODE: 0 = f32, 1 = bf16, 2 = fp8(relu(x)/8)
template<int N, int K, int OUTMODE>
__global__ __launch_bounds__(256, 3) void k_gemm_mx(const unsigned char* __restrict__ A,
                                                    const unsigned char* __restrict__ Bt,
                                                    const float* __restrict__ bias,
                                                    void* __restrict__ C) {
    constexpr int LDK = 80;   // padded row stride (64 data + 16)
    __shared__ unsigned char sA[2][128 * LDK];
    __shared__ unsigned char sB[2][128 * LDK];
    const int tid  = threadIdx.x;
    const int lane = tid & 63;
    const int wave = tid >> 6;
    const int half = lane >> 5;   // K-half within 64-wide step
    const int r32  = lane & 31;   // row/col within 32x32 tile
    const size_t bm = (size_t)blockIdx.x * 128;   // M on x: XCD locality for A
    const size_t bn = (size_t)blockIdx.y * 128;
    const int wm = (wave & 1) * 64;
    const int wn = (wave >> 1) * 64;

    f32x16 acc[2][2] = {};

    // staging: 128 rows x 64 B per matrix per step; thread t -> rows r0, r0+64, col qq*16
    const int r0 = tid >> 2;
    const int qq = tid & 3;
    const unsigned char* gA0 = A  + (bm + r0)      * (size_t)K + qq * 16;
    const unsigned char* gA1 = A  + (bm + r0 + 64) * (size_t)K + qq * 16;
    const unsigned char* gB0 = Bt + (bn + r0)      * (size_t)K + qq * 16;
    const unsigned char* gB1 = Bt + (bn + r0 + 64) * (size_t)K + qq * 16;
    const int w0 = r0 * LDK + qq * 16;
    const int w1 = (r0 + 64) * LDK + qq * 16;

    i32x4 a0, a1, b0, b1;
    a0 = *(const i32x4*)(gA0);
    a1 = *(const i32x4*)(gA1);
    b0 = *(const i32x4*)(gB0);
    b1 = *(const i32x4*)(gB1);
    int buf = 0;
    *(i32x4*)(&sA[0][w0]) = a0;
    *(i32x4*)(&sA[0][w1]) = a1;
    *(i32x4*)(&sB[0][w0]) = b0;
    *(i32x4*)(&sB[0][w1]) = b1;
    __syncthreads();

    for (int k0 = 0; k0 < K; k0 += 64) {
        const bool has_next = (k0 + 64) < K;
        if (has_next) {   // prefetch next slice into VGPRs; consumed at ds_write below
            a0 = *(const i32x4*)(gA0 + k0 + 64);
            a1 = *(const i32x4*)(gA1 + k0 + 64);
            b0 = *(const i32x4*)(gB0 + k0 + 64);
            b1 = *(const i32x4*)(gB1 + k0 + 64);
        }

        const unsigned char* pA = sA[buf];
        const unsigned char* pB = sB[buf];
        i32x8 af[2], bf[2];
        #pragma unroll
        for (int mi = 0; mi < 2; ++mi) {
            const unsigned char* p = pA + (wm + mi * 32 + r32) * LDK + half * 32;
            i32x4 lo = *(const i32x4*)(p);
            i32x4 hi = *(const i32x4*)(p + 16);
            af[mi] = __builtin_shufflevector(lo, hi, 0, 1, 2, 3, 4, 5, 6, 7);
        }
        #pragma unroll
        for (int ni = 0; ni < 2; ++ni) {
            const unsigned char* p = pB + (wn + ni * 32 + r32) * LDK + half * 32;
            i32x4 lo = *(const i32x4*)(p);
            i32x4 hi = *(const i32x4*)(p + 16);
            bf[ni] = __builtin_shufflevector(lo, hi, 0, 1, 2, 3, 4, 5, 6, 7);
        }
        #pragma unroll
        for (int mi = 0; mi < 2; ++mi)
            #pragma unroll
            for (int ni = 0; ni < 2; ++ni)
                acc[mi][ni] = __builtin_amdgcn_mfma_scale_f32_32x32x64_f8f6f4(
                    af[mi], bf[ni], acc[mi][ni],
                    0 /*cbsz: fp8*/, 0 /*blgp: fp8*/,
                    0, 0x7F7F7F7F, 0, 0x7F7F7F7F);   // e8m0 127 = x1.0 scales

        if (has_next) {
            buf ^= 1;
            *(i32x4*)(&sA[buf][w0]) = a0;
            *(i32x4*)(&sA[buf][w1]) = a1;
            *(i32x4*)(&sB[buf][w0]) = b0;
            *(i32x4*)(&sB[buf][w1]) = b1;
        }
        __syncthreads();
    }

    // epilogue: 32x32 D layout: col = r32, row = (reg&3) + 8*(reg>>2) + 4*half
    #pragma unroll
    for (int mi = 0; mi < 2; ++mi) {
        #pragma unroll
        for (int reg = 0; reg < 16; ++reg) {
            size_t row = bm + wm + mi * 32 + (reg & 3) + 8 * (reg >> 2) + 4 * half;
            #pragma unroll
            for (int ni = 0; ni < 2; ++ni) {
                int col = wn + ni * 32 + r32;
                float val = acc[mi][ni][reg] + bias[bn + col];
                if (OUTMODE == 2) {
                    ((unsigned char*)C)[row * N + bn + col] = to_fp8(fmaxf(val, 0.f) * 0.125f);
                } else if (OUTMODE == 1) {
                    ((bf16*)C)[row * N + bn + col] = (bf16)val;
                } else {
                    ((float*)C)[row * N + bn + col] = val;
                }
            }
        }
    }
}

extern "C" void kernel_launch(void* const* d_in, const int* in_sizes, int n_in,
                              void* d_out, int out_size, void* d_ws, size_t ws_size,
                              hipStream_t stream) {
    (void)in_sizes; (void)n_in; (void)out_size; (void)ws_size;
    const float* v   = (const float*)d_in[0];
    const float* q   = (const float*)d_in[1];
    const float* att = (const float*)d_in[2];
    const float* ru  = (const float*)d_in[3];
    const float* g1  = (const float*)d_in[4];
    const float* b1  = (const float*)d_in[5];
    const float* g2  = (const float*)d_in[6];
    const float* b2  = (const float*)d_in[7];
    const float* W1  = (const float*)d_in[8];
    const float* c1  = (const float*)d_in[9];
    const float* W2  = (const float*)d_in[10];
    const float* c2  = (const float*)d_in[11];

    float* out    = (float*)d_out;
    float* ru_out = out + (size_t)M_ROWS * H;

    char* ws = (char*)d_ws;
    float* rusum = (float*)ws;
    float* w     = (float*)(ws + 256);
    size_t off = 256 + (size_t)M_ROWS * sizeof(float);
    off = (off + 255) & ~(size_t)255;
    bf16* mm           = (bf16*)(ws + off);          off += (size_t)M_ROWS * H * 2;
    bf16* fc           = (bf16*)(ws + off);          off += (size_t)M_ROWS * H * 2;
    unsigned char* mm8 = (unsigned char*)(ws + off); off += (size_t)M_ROWS * H;
    unsigned char* W1t = (unsigned char*)(ws + off); off += (size_t)H * MID;
    unsigned char* W2t = (unsigned char*)(ws + off); off += (size_t)H * MID;
    unsigned char* h8  = (unsigned char*)(ws + off); off += (size_t)M_ROWS * MID;

    hipMemsetAsync(rusum, 0, sizeof(float), stream);
    k_rusum<<<M_ROWS / 256, 256, 0, stream>>>(ru, rusum);
    k_gate<<<BS, 64, 0, stream>>>(att, ru, rusum, w, ru_out);
    k_transpose_fp8<<<dim3(MID / 32, H / 32), dim3(32, 8), 0, stream>>>(W1, W1t, H, MID, 8.0f);
    k_transpose_fp8<<<dim3(H / 32, MID / 32), dim3(32, 8), 0, stream>>>(W2, W2t, MID, H, 8.0f);
    k_ln1<<<M_ROWS / 4, 256, 0, stream>>>((const f32x4*)v, (const f32x4*)q,
                                          (const f32x4*)g1, (const f32x4*)b1, w,
                                          (bf16x4*)mm, (int*)mm8);
    k_gemm_mx<MID, H, 2><<<dim3(M_ROWS / 128, MID / 128), 256, 0, stream>>>(mm8, W1t, c1, h8);
    k_gemm_mx<H, MID, 1><<<dim3(M_ROWS / 128, H / 128), 256, 0, stream>>>(h8, W2t, c2, fc);
    k_ln2<<<M_ROWS / 4, 256, 0, stream>>>(out, (const bf16x4*)fc, (const bf16x4*)mm,
                                          (const f32x4*)g2, (const f32x4*)b2);
}